// Round 2
// baseline (431.145 us; speedup 1.0000x reference)
//
#include <hip/hip_runtime.h>

// 2-level inverse Haar DWT, fully fused.
// Shapes (fp32): yl (16,64,64,64), yh0 (16,64,3,128,128), yh1 (16,64,3,64,64)
// out (16,64,256,256).
// Haar k=2 stride-2 transposed conv has non-overlapping placements:
//   out[2i+a][2j+b] = 0.5*(ll + sa*lh + sb*hl + sa*sb*hh), sa=+/-1 by a, sb by b.
// One thread = one coarse (i,j) -> 2x2 ll1 patch -> 4x4 output patch.
// Traffic: 64 B read + 64 B written per thread, all coalesced. Memory-bound.

#define NC_TOT (16 * 64)   // N*C
#define HC 64              // coarse H=W
#define HM 128             // mid (level-1 output)
#define HO 256             // final output

__global__ __launch_bounds__(256) void idwt2_haar_fused(
    const float* __restrict__ yl,
    const float* __restrict__ yh0,
    const float* __restrict__ yh1,
    float* __restrict__ out)
{
    const int tid = threadIdx.x;
    const int j  = tid & 63;        // coarse col 0..63
    const int il = tid >> 6;        // 0..3
    const int blk = blockIdx.x;     // 0 .. NC_TOT*16 - 1
    const int nc = blk >> 4;        // n*C + c
    const int i  = ((blk & 15) << 2) + il;   // coarse row 0..63

    // ---- level 1 inputs (all coalesced 4B/lane) ----
    const float ll = yl[(nc * HC + i) * HC + j];
    const int h1 = (nc * 3 * HC + i) * HC + j;     // subband stride = HC*HC
    const float lh = yh1[h1];
    const float hl = yh1[h1 + HC * HC];
    const float hh = yh1[h1 + 2 * HC * HC];

    // ---- level-1 butterfly: ll1 values at rows 2i+a, cols 2j+b ----
    float L[2][2];
    L[0][0] = 0.5f * (ll + lh + hl + hh);
    L[0][1] = 0.5f * (ll + lh - hl - hh);
    L[1][0] = 0.5f * (ll - lh + hl - hh);
    L[1][1] = 0.5f * (ll - lh - hl + hh);

    // ---- level 0: yh0 float2 at rows 2i+a, cols (2j, 2j+1) ----
    const float2* __restrict__ yh0v = (const float2*)yh0;
    float4* __restrict__ outv = (float4*)out;

    #pragma unroll
    for (int a = 0; a < 2; ++a) {
        const int p = 2 * i + a;                       // mid row
        const int rb = (nc * 3 * HM + p) * (HM / 2) + j;  // float2 index
        const float2 lh0 = yh0v[rb];
        const float2 hl0 = yh0v[rb + HM * (HM / 2)];
        const float2 hh0 = yh0v[rb + 2 * HM * (HM / 2)];

        #pragma unroll
        for (int da = 0; da < 2; ++da) {
            const float s = da ? -1.0f : 1.0f;
            // b=0 -> out cols 4j, 4j+1 ; b=1 -> out cols 4j+2, 4j+3
            const float e0 = L[a][0] + s * lh0.x;
            const float f0 = hl0.x + s * hh0.x;
            const float e1 = L[a][1] + s * lh0.y;
            const float f1 = hl0.y + s * hh0.y;
            float4 o;
            o.x = 0.5f * (e0 + f0);
            o.y = 0.5f * (e0 - f0);
            o.z = 0.5f * (e1 + f1);
            o.w = 0.5f * (e1 - f1);
            const int r = 4 * i + 2 * a + da;          // output row
            outv[(nc * HO + r) * (HO / 4) + j] = o;
        }
    }
}

extern "C" void kernel_launch(void* const* d_in, const int* in_sizes, int n_in,
                              void* d_out, int out_size, void* d_ws, size_t ws_size,
                              hipStream_t stream) {
    const float* yl  = (const float*)d_in[0];
    const float* yh0 = (const float*)d_in[1];
    const float* yh1 = (const float*)d_in[2];
    // d_in[3] = filts, hardcoded (Haar: all coefficients +/- 1/sqrt(2), s^2 = 0.5)
    float* out = (float*)d_out;

    const int blocks = NC_TOT * 16;   // 16384 blocks x 256 threads = one thread per coarse pos
    idwt2_haar_fused<<<blocks, 256, 0, stream>>>(yl, yh0, yh1, out);
}